// Round 7
// baseline (91.254 us; speedup 1.0000x reference)
//
#include <hip/hip_runtime.h>
#include <hip/hip_bf16.h>

typedef __bf16 bf16_t;
typedef bf16_t bf16x2 __attribute__((ext_vector_type(2)));
typedef bf16_t bf16x4 __attribute__((ext_vector_type(4)));
typedef bf16_t bf16x8 __attribute__((ext_vector_type(8)));
typedef float  floatx4  __attribute__((ext_vector_type(4)));
typedef float  floatx16 __attribute__((ext_vector_type(16)));

constexpr int B = 8, N = 2048, D = 64;
constexpr int TSTR = 65;   // prepass transpose stride (fp32)

// --- prepass: z=0: K fp32->bf16 (same layout). z=1: V (b,n,d) fp32 -> Vt (b,d,n) bf16 ---
__global__ __launch_bounds__(256)
void prepass_kernel(const float* __restrict__ k, const float* __restrict__ v,
                    bf16_t* __restrict__ kb, bf16_t* __restrict__ vt) {
    __shared__ float t[64 * TSTR];
    const int tid = threadIdx.x;
    const int r0  = blockIdx.x * 64;
    const int b   = blockIdx.y;
    if (blockIdx.z == 0) {
        const float* src = k + ((size_t)b * N + r0) * D;
        bf16_t* dst = kb + ((size_t)b * N + r0) * D;
        #pragma unroll
        for (int p = 0; p < 4; ++p) {
            int e = (tid + p * 256) * 4;
            floatx4 f = *(const floatx4*)(src + e);
            bf16x4 o;
            #pragma unroll
            for (int j = 0; j < 4; ++j) o[j] = (bf16_t)f[j];
            *(bf16x4*)(dst + e) = o;
        }
    } else {
        const float* vb = v + ((size_t)b * N + r0) * D;
        #pragma unroll
        for (int p = 0; p < 4; ++p) {
            int e = (tid + p * 256) * 4;
            int row = e >> 6, col = e & 63;
            floatx4 f = *(const floatx4*)(vb + e);
            #pragma unroll
            for (int j = 0; j < 4; ++j) t[(col + j) * TSTR + row] = f[j];
        }
        __syncthreads();
        bf16_t* ob = vt + (size_t)b * D * N + r0;
        #pragma unroll
        for (int p = 0; p < 4; ++p) {
            int e = (tid + p * 256) * 4;
            int drow = e >> 6, kcol = e & 63;
            bf16x4 o;
            #pragma unroll
            for (int j = 0; j < 4; ++j) o[j] = (bf16_t)t[drow * TSTR + kcol + j];
            *(bf16x4*)(ob + (size_t)drow * N + kcol) = o;
        }
    }
}

// --- flash attention, transposed (S^T = K Q^T, O^T = V^T P^T), BN=256, 8 waves ---
// grid (N/32, B) = 512 blocks = 2/CU resident x 8 waves = 4 waves/SIMD.
// K[256x64] + Vt[64x256] bf16 in 64KB LDS, 16B-granule XOR swizzle (g^=row&7):
// conflict-free staging writes AND fragment reads, no padding.
__global__ __launch_bounds__(512, 4)
void attn_kernel(const float* __restrict__ q, const bf16_t* __restrict__ kb,
                 const bf16_t* __restrict__ vt, float* __restrict__ out) {
    __shared__ char smem[65536];
    bf16_t* lds_k = (bf16_t*)smem;              // [256][64] swizzled, 32 KB
    bf16_t* lds_v = (bf16_t*)(smem + 32768);    // [64][256] swizzled, 32 KB
    float*  o_buf = (float*)smem;               // post-loop overlay: [7][64][32] = 57344 B
    float*  l_buf = (float*)(smem + 57344);     // post-loop overlay: [7][32]

    const int tid  = threadIdx.x;
    const int lane = tid & 63;
    const int cg   = tid >> 6;     // wave = kv slice of 32 within the 256-tile
    const int h    = lane >> 5;    // half-wave
    const int l31  = lane & 31;
    const int sw   = l31 & 7;      // swizzle key for fragment reads (row&7 == l31&7)

    const int b  = blockIdx.y;
    const int q0 = blockIdx.x * 32;

    const bf16_t* kbb = kb + (size_t)b * N * D;
    const bf16_t* vbb = vt + (size_t)b * D * N;

    // Q B-frags fp32->bf16: B[k=d][n=q=l31], k = h*8+j within each d-slice of 16
    bf16x8 qf[4];
    {
        const float* qp = q + ((size_t)b * N + q0 + l31) * D + h * 8;
        #pragma unroll
        for (int kd = 0; kd < 4; ++kd) {
            floatx4 f0 = *(const floatx4*)(qp + kd * 16);
            floatx4 f1 = *(const floatx4*)(qp + kd * 16 + 4);
            bf16x8 t;
            #pragma unroll
            for (int j = 0; j < 4; ++j) { t[j] = (bf16_t)f0[j]; t[j + 4] = (bf16_t)f1[j]; }
            qf[kd] = t;
        }
    }

    floatx16 o_acc[2];
    #pragma unroll
    for (int d = 0; d < 2; ++d)
        #pragma unroll
        for (int i = 0; i < 16; ++i) o_acc[d][i] = 0.f;
    float l_run = 0.f;   // softmax denom for q = q0+l31 over this wave's kv rows

    // prefetch tile 0: K 256x64 contiguous; Vt rows (d) stride N
    bf16x8 kreg[4], vreg[4];
    #pragma unroll
    for (int p = 0; p < 4; ++p) {
        int e = (tid + p * 512) * 8;                       // 0..16383
        kreg[p] = *(const bf16x8*)(kbb + e);
        vreg[p] = *(const bf16x8*)(vbb + (size_t)(e >> 8) * N + (e & 255));
    }

    #pragma unroll 1
    for (int it = 0; it < N / 256; ++it) {
        __syncthreads();   // prev iter's frag reads done before overwrite
        #pragma unroll
        for (int p = 0; p < 4; ++p) {
            int e  = (tid + p * 512) * 8;
            int kr = e >> 6, kg = (e >> 3) & 7;            // K: row, granule
            *(bf16x8*)&lds_k[kr * 64 + ((kg ^ (kr & 7)) << 3)] = kreg[p];
            int vr = e >> 8, vg = (e >> 3) & 31;           // V: d-row, granule
            *(bf16x8*)&lds_v[vr * 256 + ((vg ^ (vr & 7)) << 3)] = vreg[p];
        }
        __syncthreads();
        if (it + 1 < N / 256) {
            const int kv1 = (it + 1) * 256;
            #pragma unroll
            for (int p = 0; p < 4; ++p) {
                int e = (tid + p * 512) * 8;
                kreg[p] = *(const bf16x8*)(kbb + (size_t)kv1 * D + e);
                vreg[p] = *(const bf16x8*)(vbb + (size_t)(e >> 8) * N + kv1 + (e & 255));
            }
        }

        // S^T = K Q^T (32kv x 32q): A = K-frag (swizzled LDS), B = Q-frag
        floatx16 s;
        #pragma unroll
        for (int i = 0; i < 16; ++i) s[i] = 0.f;
        #pragma unroll
        for (int kd = 0; kd < 4; ++kd) {
            bf16x8 kf = *(const bf16x8*)&lds_k[(cg * 32 + l31) * 64 + (((2 * kd + h) ^ sw) << 3)];
            s = __builtin_amdgcn_mfma_f32_32x32x16_bf16(kf, qf[kd], s, 0, 0, 0);
        }

        // scale + equality-mask (attn==0 -> -inf -> weight 0) + exp; pack bf16 pairs
        int q8[8];
        #pragma unroll
        for (int g = 0; g < 8; ++g) {
            union { int i; bf16x2 h2; } u;
            #pragma unroll
            for (int j = 0; j < 2; ++j) {
                float x = s[2 * g + j] * 0.125f;
                float p = (x == 0.0f) ? 0.0f : __expf(x);
                l_run += p;
                u.h2[j] = (bf16_t)p;
            }
            q8[g] = u.i;
        }

        // O^T += V^T P^T : A = Vt-frag (swizzled LDS), B = P^T-frag via half-wave exchange
        #pragma unroll
        for (int s2 = 0; s2 < 2; ++s2) {
            int r0 = __shfl_xor(q8[4 * s2 + 0], 32);
            int r1 = __shfl_xor(q8[4 * s2 + 1], 32);
            int r2 = __shfl_xor(q8[4 * s2 + 2], 32);
            int r3 = __shfl_xor(q8[4 * s2 + 3], 32);
            union { int i4[4]; bf16x8 v; } bf;
            bf.i4[0] = h ? r2 : q8[4 * s2 + 0];
            bf.i4[1] = h ? r3 : q8[4 * s2 + 1];
            bf.i4[2] = h ? q8[4 * s2 + 2] : r0;
            bf.i4[3] = h ? q8[4 * s2 + 3] : r1;
            #pragma unroll
            for (int dblk = 0; dblk < 2; ++dblk) {
                bf16x8 va = *(const bf16x8*)&lds_v[(dblk * 32 + l31) * 256 +
                                                   (((cg * 4 + s2 * 2 + h) ^ sw) << 3)];
                o_acc[dblk] = __builtin_amdgcn_mfma_f32_32x32x16_bf16(va, bf.v, o_acc[dblk], 0, 0, 0);
            }
        }
    }

    __syncthreads();   // all loop LDS reads done; smem becomes o_buf / l_buf

    // complete this wave's denom: partner half holds the other 16 kv rows of the slice
    l_run += __shfl_xor(l_run, 32);

    // merge the 8 kv-slice partials (plain sums)
    if (cg > 0) {
        float* ob = o_buf + (size_t)(cg - 1) * 64 * 32;
        #pragma unroll
        for (int dblk = 0; dblk < 2; ++dblk)
            #pragma unroll
            for (int i = 0; i < 16; ++i) {
                const int d = (i & 3) + 8 * (i >> 2) + 4 * h + dblk * 32;
                ob[d * 32 + l31] = o_acc[dblk][i];
            }
        if (h == 0) l_buf[(cg - 1) * 32 + l31] = l_run;
    }
    __syncthreads();
    if (cg == 0) {
        float lsum = l_run;
        #pragma unroll
        for (int gg = 0; gg < 7; ++gg) lsum += l_buf[gg * 32 + l31];
        const float inv_l = 1.0f / lsum;
        float* op = out + ((size_t)b * N + q0 + l31) * D;
        #pragma unroll
        for (int dblk = 0; dblk < 2; ++dblk)
            #pragma unroll
            for (int g = 0; g < 4; ++g) {
                const int d0 = 8 * g + 4 * h + dblk * 32;   // 4 consecutive d per reg group
                floatx4 o4;
                #pragma unroll
                for (int j = 0; j < 4; ++j) {
                    float sum = o_acc[dblk][4 * g + j];
                    #pragma unroll
                    for (int gg = 0; gg < 7; ++gg)
                        sum += o_buf[(size_t)gg * 64 * 32 + (d0 + j) * 32 + l31];
                    o4[j] = sum * inv_l;
                }
                *(floatx4*)(op + d0) = o4;
            }
    }
}

extern "C" void kernel_launch(void* const* d_in, const int* in_sizes, int n_in,
                              void* d_out, int out_size, void* d_ws, size_t ws_size,
                              hipStream_t stream) {
    const float* q = (const float*)d_in[0];
    const float* k = (const float*)d_in[1];
    const float* v = (const float*)d_in[2];
    float* out = (float*)d_out;
    bf16_t* kb = (bf16_t*)d_ws;                                   // 2 MB
    bf16_t* vt = (bf16_t*)((char*)d_ws + (size_t)B * N * D * 2);  // 2 MB

    hipLaunchKernelGGL(prepass_kernel, dim3(N / 64, B, 2), dim3(256), 0, stream, k, v, kb, vt);
    hipLaunchKernelGGL(attn_kernel, dim3(N / 32, B), dim3(512), 0, stream, q, kb, vt, out);
}